// Round 11
// baseline (216.582 us; speedup 1.0000x reference)
//
#include <hip/hip_runtime.h>

#define NEG_INF -9e15f
#define ALPHA 0.2f

// R11 = R10 (202.9us: 768 blocks, per-wave register prefetch, nt hints,
// grouped ent-then-wr bursts, no barriers) + CONTIGUOUS chunk mapping:
// each of the 3072 streams owns a contiguous run of 13-14 rows (streams
// 0..63 get 14: 64*14 + 3008*13 = 40000). Successive bursts from a wave
// then continue the same DRAM page run instead of jumping ~39MB.
// Isolates the chunking variable that R7 confounded with an occupancy cut.
typedef float floatx4 __attribute__((ext_vector_type(4)));

constexpr int K = 32, D = 100, KD = K * D;     // 3200 floats, 800 float4
constexpr int NBLK = 768;                      // 3 blocks/CU (LDS-bound)
constexpr int WPB = 4;
constexpr int NSTREAM = NBLK * WPB;            // 3072 streams
constexpr int BASECHUNK = 13;                  // +1 for streams < 64

// W4[jj*400 + d*4 + c] = Wout[d][4*jj+c]  (jj<25, d<100, c<4) -> 40 KB
__global__ __launch_bounds__(256) void pack_wout(
    const float* __restrict__ W, float* __restrict__ W4)
{
    int idx = blockIdx.x * 256 + threadIdx.x;
    if (idx < D * D) {
        int jj = idx / 400;
        int r  = idx - jj * 400;
        int d  = r >> 2;
        int c  = r & 3;
        W4[idx] = W[d * D + 4 * jj + c];
    }
}

__global__ __launch_bounds__(256) void gat_wave_pipe(
    const float* __restrict__ item,   // [N, D]
    const float* __restrict__ ent,    // [N, K, D]
    const float* __restrict__ wr,     // [N, K, D]
    const int*   __restrict__ adj,    // [N, K]
    const float* __restrict__ W4,     // packed Wout in ws (40 KB, hot/cached)
    const float* __restrict__ bout,   // [D]
    float* __restrict__ out,          // [N, D]
    int N)
{
    __shared__ floatx4 sWe4[WPB * (KD / 4)];   // 51200 B, per-wave regions

    const int t   = threadIdx.x;
    const int wid = t >> 6;
    const int l   = t & 63;
    const int k   = l & 31;          // k-row this lane reduces in ksum
    const int h   = l >> 5;          // half of the k-row
    const bool bl = (l < 36);
    const int lb  = bl ? l : 35;

    floatx4* we4 = sWe4 + wid * (KD / 4);
    const float* we = reinterpret_cast<const float*>(we4);
    const floatx4* W4v = reinterpret_cast<const floatx4*>(W4);

    const float bouta = bout[l];
    const float boutb = bout[64 + lb];

    // contiguous chunk per stream: streams 0..63 own 14 rows, rest 13
    const int s  = blockIdx.x * WPB + wid;
    const int extra = (s < 64) ? s : 64;
    const int n0 = s * BASECHUNK + extra;
    const int n1 = n0 + BASECHUNK + (s < 64 ? 1 : 0);

    int n = n0;

    floatx4 a[12], b[12], at, bt;
    int   adjv; float itma, itmb;

// Grouped issue: full ent burst first, then full wr burst.
#define LOADROW(NN, ADJ, ITA, ITB) do {                                        \
        const floatx4* e4_ = reinterpret_cast<const floatx4*>(ent + (size_t)(NN) * KD); \
        const floatx4* w4_ = reinterpret_cast<const floatx4*>(wr  + (size_t)(NN) * KD); \
        _Pragma("unroll")                                                      \
        for (int j = 0; j < 12; ++j)                                           \
            a[j] = __builtin_nontemporal_load(e4_ + l + 64 * j);               \
        if (l < 32)                                                            \
            at = __builtin_nontemporal_load(e4_ + 768 + l);                    \
        _Pragma("unroll")                                                      \
        for (int j = 0; j < 12; ++j)                                           \
            b[j] = __builtin_nontemporal_load(w4_ + l + 64 * j);               \
        if (l < 32)                                                            \
            bt = __builtin_nontemporal_load(w4_ + 768 + l);                    \
        ADJ = __builtin_nontemporal_load(adj + (size_t)(NN) * K + k);          \
        ITA = __builtin_nontemporal_load(item + (size_t)(NN) * D + l);         \
        ITB = __builtin_nontemporal_load(item + (size_t)(NN) * D + 64 + lb);   \
    } while (0)

    LOADROW(n, adjv, itma, itmb);

    for (;;) {
        // ---- phase 1: products -> per-wave LDS (consumes a/b) ----
        #pragma unroll
        for (int j = 0; j < 12; ++j)
            we4[l + 64 * j] = a[j] * b[j];
        if (l < 32)
            we4[768 + l] = at * bt;

        // ---- issue next row's loads NOW; phases 2-4 hide the latency ----
        const int n2 = n + 1;
        const bool more = (n2 < n1);
        int nadj = 0; float nitma = 0.f, nitmb = 0.f;
        if (more) LOADROW(n2, nadj, nitma, nitmb);

        // ---- ksum: lane (k,h) reads its half of k-row from LDS ----
        float sv = 0.f;
        {
            const floatx4* base = we4 + k * 25 + (h ? 13 : 0);
            #pragma unroll
            for (int j = 0; j < 12; ++j) {
                floatx4 q = base[j];
                sv += (q.x + q.y) + (q.z + q.w);
            }
            if (h == 0) {
                floatx4 q = base[12];
                sv += (q.x + q.y) + (q.z + q.w);
            }
        }
        sv += __shfl_xor(sv, 32);

        // ---- softmax over K in registers ----
        float e  = sv > 0.f ? sv : ALPHA * sv;
        float lg = adjv > 0 ? e : NEG_INF;
        float m = lg;
        #pragma unroll
        for (int off = 16; off; off >>= 1)
            m = fmaxf(m, __shfl_xor(m, off, 32));
        float p = expf(lg - m);
        float sm = p;
        #pragma unroll
        for (int off = 16; off; off >>= 1)
            sm += __shfl_xor(sm, off, 32);
        const float att = p / sm;          // lane holds att[l&31]

        // ---- phase 3: h[d] = sum_k att[k]*We[k][d]; lane owns d=l, 64+lb ----
        float ha = 0.f, hb = 0.f;
        #pragma unroll
        for (int kk = 0; kk < K; ++kk) {
            float ak = __shfl(att, kk);
            ha = fmaf(ak, we[kk * D + l], ha);
            hb = fmaf(ak, we[kk * D + 64 + lb], hb);
        }

        // ---- phase 4: out = h . WoutT + b + item via packed W4 ----
        float aa = 0.f, ab = 0.f;
        #pragma unroll
        for (int jj = 0; jj < 25; ++jj) {
            const floatx4 wa = W4v[jj * 100 + l];
            const floatx4 wb = W4v[jj * 100 + 64 + lb];
            float h0, h1, h2, h3;
            {
                const int j = 4 * jj;
                h0 = (j + 0 < 64) ? __shfl(ha, j + 0) : __shfl(hb, j - 64);
                h1 = (j + 1 < 64) ? __shfl(ha, j + 1) : __shfl(hb, j - 63);
                h2 = (j + 2 < 64) ? __shfl(ha, j + 2) : __shfl(hb, j - 62);
                h3 = (j + 3 < 64) ? __shfl(ha, j + 3) : __shfl(hb, j - 61);
            }
            aa = fmaf(h0, wa.x, aa); aa = fmaf(h1, wa.y, aa);
            aa = fmaf(h2, wa.z, aa); aa = fmaf(h3, wa.w, aa);
            ab = fmaf(h0, wb.x, ab); ab = fmaf(h1, wb.y, ab);
            ab = fmaf(h2, wb.z, ab); ab = fmaf(h3, wb.w, ab);
        }

        __builtin_nontemporal_store(aa + bouta + itma, out + (size_t)n * D + l);
        if (bl) __builtin_nontemporal_store(ab + boutb + itmb,
                                            out + (size_t)n * D + 64 + l);

        if (!more) break;
        n = n2;
        adjv = nadj; itma = nitma; itmb = nitmb;
    }
#undef LOADROW
}

extern "C" void kernel_launch(void* const* d_in, const int* in_sizes, int n_in,
                              void* d_out, int out_size, void* d_ws, size_t ws_size,
                              hipStream_t stream) {
    const float* item = (const float*)d_in[0];
    const float* ent  = (const float*)d_in[1];
    const float* wr   = (const float*)d_in[2];
    const int*   adj  = (const int*)d_in[3];
    const float* Wout = (const float*)d_in[4];
    const float* bout = (const float*)d_in[5];
    float* out = (float*)d_out;
    float* W4  = (float*)d_ws;     // 40 KB packed Wout

    const int N = 40000;
    pack_wout<<<(D * D + 255) / 256, 256, 0, stream>>>(Wout, W4);
    gat_wave_pipe<<<NBLK, 256, 0, stream>>>(item, ent, wr, adj, W4, bout, out, N);
}

// Round 12
// 201.382 us; speedup vs baseline: 1.0755x; 1.0755x over previous
//
#include <hip/hip_runtime.h>

#define NEG_INF -9e15f
#define ALPHA 0.2f

// R12 = exact revert to R10 (202.9us best): 768 blocks, STRIDED streams,
// per-wave register prefetch, nt hints, grouped ent-then-wr bursts, no
// barriers. R11 proved contiguous chunking is -6.7% (concurrent-request
// page locality beats per-stream sequentiality: strided keeps all 3072
// streams' requests inside a moving ~39MB window).
//
// Final ledger (dur_us): naive-block 476 -> wave-per-row 312 -> +prefetch
// (no spill) 223 -> +nt 217.5 -> +grouped bursts 202.9 = 5.28 TB/s demand
// (84% of 6.29 TB/s copy ceiling; ideal-BW floor is ~170us).
typedef float floatx4 __attribute__((ext_vector_type(4)));

constexpr int K = 32, D = 100, KD = K * D;     // 3200 floats, 800 float4
constexpr int NBLK = 768;                      // 3 blocks/CU (LDS-bound)
constexpr int WPB = 4;
constexpr int NSTREAM = NBLK * WPB;            // 3072 row streams

// W4[jj*400 + d*4 + c] = Wout[d][4*jj+c]  (jj<25, d<100, c<4) -> 40 KB
__global__ __launch_bounds__(256) void pack_wout(
    const float* __restrict__ W, float* __restrict__ W4)
{
    int idx = blockIdx.x * 256 + threadIdx.x;
    if (idx < D * D) {
        int jj = idx / 400;
        int r  = idx - jj * 400;
        int d  = r >> 2;
        int c  = r & 3;
        W4[idx] = W[d * D + 4 * jj + c];
    }
}

__global__ __launch_bounds__(256) void gat_wave_pipe(
    const float* __restrict__ item,   // [N, D]
    const float* __restrict__ ent,    // [N, K, D]
    const float* __restrict__ wr,     // [N, K, D]
    const int*   __restrict__ adj,    // [N, K]
    const float* __restrict__ W4,     // packed Wout in ws (40 KB, hot/cached)
    const float* __restrict__ bout,   // [D]
    float* __restrict__ out,          // [N, D]
    int N)
{
    __shared__ floatx4 sWe4[WPB * (KD / 4)];   // 51200 B, per-wave regions

    const int t   = threadIdx.x;
    const int wid = t >> 6;
    const int l   = t & 63;
    const int k   = l & 31;          // k-row this lane reduces in ksum
    const int h   = l >> 5;          // half of the k-row
    const bool bl = (l < 36);
    const int lb  = bl ? l : 35;

    floatx4* we4 = sWe4 + wid * (KD / 4);
    const float* we = reinterpret_cast<const float*>(we4);
    const floatx4* W4v = reinterpret_cast<const floatx4*>(W4);

    const float bouta = bout[l];
    const float boutb = bout[64 + lb];

    int n = blockIdx.x * WPB + wid;

    floatx4 a[12], b[12], at, bt;
    int   adjv; float itma, itmb;

// Grouped issue: full ent burst first, then full wr burst.
#define LOADROW(NN, ADJ, ITA, ITB) do {                                        \
        const floatx4* e4_ = reinterpret_cast<const floatx4*>(ent + (size_t)(NN) * KD); \
        const floatx4* w4_ = reinterpret_cast<const floatx4*>(wr  + (size_t)(NN) * KD); \
        _Pragma("unroll")                                                      \
        for (int j = 0; j < 12; ++j)                                           \
            a[j] = __builtin_nontemporal_load(e4_ + l + 64 * j);               \
        if (l < 32)                                                            \
            at = __builtin_nontemporal_load(e4_ + 768 + l);                    \
        _Pragma("unroll")                                                      \
        for (int j = 0; j < 12; ++j)                                           \
            b[j] = __builtin_nontemporal_load(w4_ + l + 64 * j);               \
        if (l < 32)                                                            \
            bt = __builtin_nontemporal_load(w4_ + 768 + l);                    \
        ADJ = __builtin_nontemporal_load(adj + (size_t)(NN) * K + k);          \
        ITA = __builtin_nontemporal_load(item + (size_t)(NN) * D + l);         \
        ITB = __builtin_nontemporal_load(item + (size_t)(NN) * D + 64 + lb);   \
    } while (0)

    LOADROW(n, adjv, itma, itmb);

    for (;;) {
        // ---- phase 1: products -> per-wave LDS (consumes a/b) ----
        #pragma unroll
        for (int j = 0; j < 12; ++j)
            we4[l + 64 * j] = a[j] * b[j];
        if (l < 32)
            we4[768 + l] = at * bt;

        // ---- issue next row's loads NOW; phases 2-4 hide the latency ----
        const int n2 = n + NSTREAM;
        const bool more = (n2 < N);
        int nadj = 0; float nitma = 0.f, nitmb = 0.f;
        if (more) LOADROW(n2, nadj, nitma, nitmb);

        // ---- ksum: lane (k,h) reads its half of k-row from LDS ----
        float sv = 0.f;
        {
            const floatx4* base = we4 + k * 25 + (h ? 13 : 0);
            #pragma unroll
            for (int j = 0; j < 12; ++j) {
                floatx4 q = base[j];
                sv += (q.x + q.y) + (q.z + q.w);
            }
            if (h == 0) {
                floatx4 q = base[12];
                sv += (q.x + q.y) + (q.z + q.w);
            }
        }
        sv += __shfl_xor(sv, 32);

        // ---- softmax over K in registers ----
        float e  = sv > 0.f ? sv : ALPHA * sv;
        float lg = adjv > 0 ? e : NEG_INF;
        float m = lg;
        #pragma unroll
        for (int off = 16; off; off >>= 1)
            m = fmaxf(m, __shfl_xor(m, off, 32));
        float p = expf(lg - m);
        float sm = p;
        #pragma unroll
        for (int off = 16; off; off >>= 1)
            sm += __shfl_xor(sm, off, 32);
        const float att = p / sm;          // lane holds att[l&31]

        // ---- phase 3: h[d] = sum_k att[k]*We[k][d]; lane owns d=l, 64+lb ----
        float ha = 0.f, hb = 0.f;
        #pragma unroll
        for (int kk = 0; kk < K; ++kk) {
            float ak = __shfl(att, kk);
            ha = fmaf(ak, we[kk * D + l], ha);
            hb = fmaf(ak, we[kk * D + 64 + lb], hb);
        }

        // ---- phase 4: out = h . WoutT + b + item via packed W4 ----
        float aa = 0.f, ab = 0.f;
        #pragma unroll
        for (int jj = 0; jj < 25; ++jj) {
            const floatx4 wa = W4v[jj * 100 + l];
            const floatx4 wb = W4v[jj * 100 + 64 + lb];
            float h0, h1, h2, h3;
            {
                const int j = 4 * jj;
                h0 = (j + 0 < 64) ? __shfl(ha, j + 0) : __shfl(hb, j - 64);
                h1 = (j + 1 < 64) ? __shfl(ha, j + 1) : __shfl(hb, j - 63);
                h2 = (j + 2 < 64) ? __shfl(ha, j + 2) : __shfl(hb, j - 62);
                h3 = (j + 3 < 64) ? __shfl(ha, j + 3) : __shfl(hb, j - 61);
            }
            aa = fmaf(h0, wa.x, aa); aa = fmaf(h1, wa.y, aa);
            aa = fmaf(h2, wa.z, aa); aa = fmaf(h3, wa.w, aa);
            ab = fmaf(h0, wb.x, ab); ab = fmaf(h1, wb.y, ab);
            ab = fmaf(h2, wb.z, ab); ab = fmaf(h3, wb.w, ab);
        }

        __builtin_nontemporal_store(aa + bouta + itma, out + (size_t)n * D + l);
        if (bl) __builtin_nontemporal_store(ab + boutb + itmb,
                                            out + (size_t)n * D + 64 + l);

        if (!more) break;
        n = n2;
        adjv = nadj; itma = nitma; itmb = nitmb;
    }
#undef LOADROW
}

extern "C" void kernel_launch(void* const* d_in, const int* in_sizes, int n_in,
                              void* d_out, int out_size, void* d_ws, size_t ws_size,
                              hipStream_t stream) {
    const float* item = (const float*)d_in[0];
    const float* ent  = (const float*)d_in[1];
    const float* wr   = (const float*)d_in[2];
    const int*   adj  = (const int*)d_in[3];
    const float* Wout = (const float*)d_in[4];
    const float* bout = (const float*)d_in[5];
    float* out = (float*)d_out;
    float* W4  = (float*)d_ws;     // 40 KB packed Wout

    const int N = 40000;
    pack_wout<<<(D * D + 255) / 256, 256, 0, stream>>>(Wout, W4);
    gat_wave_pipe<<<NBLK, 256, 0, stream>>>(item, ent, wr, adj, W4, bout, out, N);
}